// Round 7
// baseline (4402.440 us; speedup 1.0000x reference)
//
#include <hip/hip_runtime.h>

// Chemprop BondMessagePassing, DEPTH=3, eval mode.
// R6: bf16-H CSR-gather path = 3.58ms; k_updb (1.5ms x2) is LDS-BW bound
// (56KB LDS per wave-chunk vs 1280cy FMA) and spends 11/21 chunks
// recomputing H0.
// R7: (1) store H0 as bf16 (k_h0b writes both copies) -> update is 10 chunks;
//     guarded by ws_size >= 355MB, fallback = proven R6 path.
//     (2) k_updb2: TE=128, 8x10 thread tile -> 2560cy FMA vs ~576cy LDS per
//     wave-chunk: FMA-bound. In-place Hb safe: all Hb[rev] prefetches are
//     consumed before the final per-chunk barrier; writes after; pairs
//     (2i,2i+1) tile-local.

#define E_EDGES 500000
#define N_NODES 50000
#define HD      160
#define BD      14
#define K1      174
#define K1P     176
#define KO      320

#define TE 64
#define KC 16
#define NC1 (K1P / KC)  // 11
#define NC2 (HD / KC)   // 10
#define TE2 128

// ---- bf16 helpers ----
__device__ __forceinline__ unsigned short f2b(float v) {
    unsigned u = __float_as_uint(v);
    u += 0x7FFFu + ((u >> 16) & 1u);
    return (unsigned short)(u >> 16);
}
__device__ __forceinline__ float b2f(unsigned short h) {
    return __uint_as_float(((unsigned)h) << 16);
}

// ---------------------------------------------------------------------------
__global__ void k_zero(float* __restrict__ p, long n)
{
    const long i = (long)blockIdx.x * 1024 + (long)threadIdx.x * 4;
    if (i + 3 < n) *(float4*)(p + i) = make_float4(0.f, 0.f, 0.f, 0.f);
}

// ---------------------------------------------------------------------------
__device__ __forceinline__
void gemm_chunk(float acc[4][10], const float At[KC][TE + 4],
                const float Wt[KC][HD + 8], int tr, int tc)
{
    #pragma unroll
    for (int k = 0; k < KC; ++k) {
        const float4 a  = *(const float4*)&At[k][tr * 4];
        const float* wp = &Wt[k][tc * 10];
        float w[10];
        #pragma unroll
        for (int j = 0; j < 10; j += 2) {
            const float2 w2 = *(const float2*)(wp + j);
            w[j] = w2.x; w[j + 1] = w2.y;
        }
        #pragma unroll
        for (int j = 0; j < 10; ++j) {
            acc[0][j] = fmaf(a.x, w[j], acc[0][j]);
            acc[1][j] = fmaf(a.y, w[j], acc[1][j]);
            acc[2][j] = fmaf(a.z, w[j], acc[2][j]);
            acc[3][j] = fmaf(a.w, w[j], acc[3][j]);
        }
    }
}

// ============================ CSR build ====================================
__global__ void k_csr_count(const int* __restrict__ dst, int* __restrict__ cnt)
{
    const int e = blockIdx.x * 256 + threadIdx.x;
    if (e < E_EDGES) atomicAdd(&cnt[dst[e]], 1);
}

#define BPT 49
__global__ __launch_bounds__(1024)
void k_csr_scan(const int* __restrict__ cnt, int* __restrict__ ptr)
{
    __shared__ int part[1024];
    const int t  = threadIdx.x;
    const int lo = t * BPT;
    const int hi = min(lo + BPT, N_NODES);
    int s = 0;
    for (int i = lo; i < hi; ++i) s += cnt[i];
    part[t] = s;
    __syncthreads();
    for (int off = 1; off < 1024; off <<= 1) {
        int v = 0;
        if (t >= off) v = part[t - off];
        __syncthreads();
        if (t >= off) part[t] += v;
        __syncthreads();
    }
    int run = (t == 0) ? 0 : part[t - 1];
    for (int i = lo; i < hi; ++i) { ptr[i] = run; run += cnt[i]; }
    if (t == 1023) ptr[N_NODES] = part[1023];
}

__global__ void k_csr_fill(const int* __restrict__ dst, const int* __restrict__ ptr,
                           int* __restrict__ cur, int* __restrict__ eid)
{
    const int e = blockIdx.x * 256 + threadIdx.x;
    if (e < E_EDGES) {
        const int d   = dst[e];
        const int pos = atomicAdd(&cur[d], 1);
        eid[ptr[d] + pos] = e;
    }
}

// ============================ shared kernels ===============================

// ---- k_h0b: Hb[e] = bf16(relu(Wi @ [x[src]; ea] + bi)); optional H0b copy.
__global__ __launch_bounds__(256, 3)
void k_h0b(const float* __restrict__ x, const float* __restrict__ ea,
           const int* __restrict__ src,
           const float* __restrict__ Wi, const float* __restrict__ bi,
           unsigned short* __restrict__ Hb, unsigned short* __restrict__ H0b)
{
    __shared__ float At[2][KC][TE + 4];
    __shared__ float Wt[2][KC][HD + 8];

    const int  t    = threadIdx.x;
    const long base = (long)blockIdx.x * TE;
    const int  se   = t >> 2;
    const int  skq  = t & 3;
    const long ge   = base + se;
    const bool ev   = ge < E_EDGES;
    const long gec  = ev ? ge : 0;
    const int  sidx = ev ? src[ge] : 0;
    const float* xrow = x  + (long)sidx * HD;
    const float* erow = ea + gec * BD;
    const int wk = t & 15, wh0 = t >> 4;
    const int tr = t >> 4, tc = t & 15;

    float4 pa; float pw[10];
    float acc[4][10];
    #pragma unroll
    for (int i = 0; i < 4; ++i)
        #pragma unroll
        for (int j = 0; j < 10; ++j) acc[i][j] = 0.f;

    auto pf_a = [&](int c) {
        const int kb = c * KC + skq * 4;
        if (kb + 3 < HD) pa = *(const float4*)(xrow + kb);
        else {
            float tmp[4];
            #pragma unroll
            for (int j = 0; j < 4; ++j) {
                const int k = kb + j;
                tmp[j] = (k < HD) ? xrow[k] : ((k < K1) ? erow[k - HD] : 0.f);
            }
            pa = make_float4(tmp[0], tmp[1], tmp[2], tmp[3]);
        }
    };
    auto pf_w = [&](int c) {
        const int k = c * KC + wk;
        #pragma unroll
        for (int m = 0; m < 10; ++m)
            pw[m] = (k < K1) ? Wi[(wh0 + 16 * m) * K1 + k] : 0.f;
    };

    pf_a(0); pf_w(0);
    for (int c = 0; c < NC1; ++c) {
        const int buf = c & 1;
        At[buf][skq * 4 + 0][se] = pa.x;
        At[buf][skq * 4 + 1][se] = pa.y;
        At[buf][skq * 4 + 2][se] = pa.z;
        At[buf][skq * 4 + 3][se] = pa.w;
        #pragma unroll
        for (int m = 0; m < 10; ++m) Wt[buf][wk][wh0 + 16 * m] = pw[m];
        __syncthreads();
        if (c + 1 < NC1) { pf_a(c + 1); pf_w(c + 1); }
        gemm_chunk(acc, At[buf], Wt[buf], tr, tc);
    }
    #pragma unroll
    for (int i = 0; i < 4; ++i) {
        const long e = base + tr * 4 + i;
        if (e >= E_EDGES) break;
        unsigned short* hp = Hb + e * HD + tc * 10;
        #pragma unroll
        for (int j = 0; j < 10; j += 2) {
            float v0 = acc[i][j]     + bi[tc * 10 + j];
            float v1 = acc[i][j + 1] + bi[tc * 10 + j + 1];
            v0 = v0 > 0.f ? v0 : 0.f;
            v1 = v1 > 0.f ? v1 : 0.f;
            const ushort2 pv = make_ushort2(f2b(v0), f2b(v1));
            *(ushort2*)(hp + j) = pv;
            if (H0b) *(ushort2*)(H0b + e * HD + tc * 10 + j) = pv;
        }
    }
}

// ---- k_segb<FINAL>: S[n] = sum_{e in in(n)} Hb[e]; gather, zero atomics. --
template <bool FINAL>
__global__ void k_segb(const unsigned short* __restrict__ Hb,
                       const int* __restrict__ ptr, const int* __restrict__ eid,
                       const float* __restrict__ x, float* __restrict__ S)
{
    const int  lane = threadIdx.x & 63;
    const int  w    = threadIdx.x >> 6;
    const long n    = (long)blockIdx.x * 4 + w;
    if (n >= N_NODES) return;
    const int p0 = ptr[n], p1 = ptr[n + 1];
    float a0 = 0.f, a1 = 0.f, a2 = 0.f;
    for (int i = p0; i < p1; ++i) {
        const unsigned short* row = Hb + (long)eid[i] * HD;
        a0 += b2f(row[lane]);
        a1 += b2f(row[64 + lane]);
        if (lane < 32) a2 += b2f(row[128 + lane]);
    }
    const long sb = n * HD;
    if (FINAL) {
        float s = a0 + a1 + a2;
        #pragma unroll
        for (int off = 32; off > 0; off >>= 1) s += __shfl_xor(s, off, 64);
        if (s == 0.f) {
            S[sb + lane]      = x[sb + lane];
            S[sb + 64 + lane] = x[sb + 64 + lane];
            if (lane < 32) S[sb + 128 + lane] = x[sb + 128 + lane];
            return;
        }
    }
    S[sb + lane]      = a0;
    S[sb + 64 + lane] = a1;
    if (lane < 32) S[sb + 128 + lane] = a2;
}

// ============================ FAT PATH (H0 stored) =========================

// ---- k_updb2: Hb[e] = bf16(relu(H0b[e] + Wh @ (S[src[e]] - Hb[e^1]) + bh))
// TE2=128 rows/block; 256 thr = 16(e) x 16(h); thread tile 8 x 10. ----
__global__ __launch_bounds__(256, 3)
void k_updb2(const float* __restrict__ S, const unsigned short* __restrict__ H0b,
             const int* __restrict__ src,
             const float* __restrict__ Wh, const float* __restrict__ bh,
             unsigned short* __restrict__ Hb)
{
    __shared__ float At[2][KC][TE2 + 4];   // 16.9 KB
    __shared__ float Wt[2][KC][HD + 8];    // 21.5 KB

    const int  t    = threadIdx.x;
    const long base = (long)blockIdx.x * TE2;
    // staging: thread t stages row sr = t>>1, k-half sq = t&1 (8 floats)
    const int  sr   = t >> 1;
    const int  sq   = t & 1;
    const long ge   = base + sr;
    const bool ev   = ge < E_EDGES;
    const long gec  = ev ? ge : 0;
    const int  sidx = ev ? src[gec] : 0;
    const float* mrow = S + (long)sidx * HD;
    const unsigned short* rrow = Hb + (gec ^ 1) * HD;   // pair-local rev edge

    const int wk = t & 15, wh0 = t >> 4;
    const int tr = t >> 4, tc = t & 15;

    float4 pa0, pa1; ushort4 pr0, pr1; float pw[10];
    float acc[8][10];
    #pragma unroll
    for (int i = 0; i < 8; ++i)
        #pragma unroll
        for (int j = 0; j < 10; ++j) acc[i][j] = 0.f;

    auto pf_m = [&](int c) {
        const int kb = c * KC + sq * 8;
        pa0 = *(const float4*)(mrow + kb);
        pa1 = *(const float4*)(mrow + kb + 4);
        pr0 = *(const ushort4*)(rrow + kb);
        pr1 = *(const ushort4*)(rrow + kb + 4);
    };
    auto pf_w = [&](int c) {
        const int k = c * KC + wk;
        #pragma unroll
        for (int m = 0; m < 10; ++m) pw[m] = Wh[(wh0 + 16 * m) * HD + k];
    };

    pf_m(0); pf_w(0);
    for (int c = 0; c < NC2; ++c) {
        const int buf = c & 1;
        const int kb  = sq * 8;
        At[buf][kb + 0][sr] = pa0.x - b2f(pr0.x);
        At[buf][kb + 1][sr] = pa0.y - b2f(pr0.y);
        At[buf][kb + 2][sr] = pa0.z - b2f(pr0.z);
        At[buf][kb + 3][sr] = pa0.w - b2f(pr0.w);
        At[buf][kb + 4][sr] = pa1.x - b2f(pr1.x);
        At[buf][kb + 5][sr] = pa1.y - b2f(pr1.y);
        At[buf][kb + 6][sr] = pa1.z - b2f(pr1.z);
        At[buf][kb + 7][sr] = pa1.w - b2f(pr1.w);
        #pragma unroll
        for (int m = 0; m < 10; ++m) Wt[buf][wk][wh0 + 16 * m] = pw[m];
        __syncthreads();
        if (c + 1 < NC2) { pf_m(c + 1); pf_w(c + 1); }
        #pragma unroll
        for (int k = 0; k < KC; ++k) {
            const float4 a0 = *(const float4*)&At[buf][k][tr * 8];
            const float4 a1 = *(const float4*)&At[buf][k][tr * 8 + 4];
            const float* wp = &Wt[buf][k][tc * 10];
            float w[10];
            #pragma unroll
            for (int j = 0; j < 10; j += 2) {
                const float2 w2 = *(const float2*)(wp + j);
                w[j] = w2.x; w[j + 1] = w2.y;
            }
            #pragma unroll
            for (int j = 0; j < 10; ++j) {
                acc[0][j] = fmaf(a0.x, w[j], acc[0][j]);
                acc[1][j] = fmaf(a0.y, w[j], acc[1][j]);
                acc[2][j] = fmaf(a0.z, w[j], acc[2][j]);
                acc[3][j] = fmaf(a0.w, w[j], acc[3][j]);
                acc[4][j] = fmaf(a1.x, w[j], acc[4][j]);
                acc[5][j] = fmaf(a1.y, w[j], acc[5][j]);
                acc[6][j] = fmaf(a1.z, w[j], acc[6][j]);
                acc[7][j] = fmaf(a1.w, w[j], acc[7][j]);
            }
        }
    }

    // epilogue: Hb = bf16(relu(H0b + acc + bh))
    #pragma unroll
    for (int i = 0; i < 8; ++i) {
        const long e = base + tr * 8 + i;
        if (e >= E_EDGES) break;
        const unsigned short* h0p = H0b + e * HD + tc * 10;
        unsigned short*       hp  = Hb  + e * HD + tc * 10;
        #pragma unroll
        for (int j = 0; j < 10; j += 2) {
            const ushort2 h0 = *(const ushort2*)(h0p + j);
            float v0 = b2f(h0.x) + acc[i][j]     + bh[tc * 10 + j];
            float v1 = b2f(h0.y) + acc[i][j + 1] + bh[tc * 10 + j + 1];
            v0 = v0 > 0.f ? v0 : 0.f;
            v1 = v1 > 0.f ? v1 : 0.f;
            *(ushort2*)(hp + j) = make_ushort2(f2b(v0), f2b(v1));
        }
    }
}

// ============================ MID PATH (R6, recompute H0) ==================

__global__ __launch_bounds__(256, 3)
void k_updb(const float* __restrict__ S,
            const float* __restrict__ x, const float* __restrict__ ea,
            const int* __restrict__ src,
            const float* __restrict__ Wi, const float* __restrict__ bi,
            const float* __restrict__ Wh, const float* __restrict__ bh,
            unsigned short* __restrict__ Hb)
{
    __shared__ float At[2][KC][TE + 4];
    __shared__ float Wt[2][KC][HD + 8];

    const int  t    = threadIdx.x;
    const long base = (long)blockIdx.x * TE;
    const int  se   = t >> 2;
    const int  skq  = t & 3;
    const long ge   = base + se;
    const bool ev   = ge < E_EDGES;
    const long gec  = ev ? ge : 0;
    const int  sidx = ev ? src[ge] : 0;
    const float* xrow = x  + (long)sidx * HD;
    const float* erow = ea + gec * BD;
    const float* mrow = S  + (long)sidx * HD;
    const unsigned short* rrow = Hb + (gec ^ 1) * HD;
    const int wk = t & 15, wh0 = t >> 4;
    const int tr = t >> 4, tc = t & 15;

    float4 pa; ushort4 pr; float pw[10];
    float acc[4][10];
    #pragma unroll
    for (int i = 0; i < 4; ++i)
        #pragma unroll
        for (int j = 0; j < 10; ++j) acc[i][j] = 0.f;

    auto pf_a1 = [&](int c) {
        const int kb = c * KC + skq * 4;
        if (kb + 3 < HD) pa = *(const float4*)(xrow + kb);
        else {
            float tmp[4];
            #pragma unroll
            for (int j = 0; j < 4; ++j) {
                const int k = kb + j;
                tmp[j] = (k < HD) ? xrow[k] : ((k < K1) ? erow[k - HD] : 0.f);
            }
            pa = make_float4(tmp[0], tmp[1], tmp[2], tmp[3]);
        }
    };
    auto pf_wi = [&](int c) {
        const int k = c * KC + wk;
        #pragma unroll
        for (int m = 0; m < 10; ++m)
            pw[m] = (k < K1) ? Wi[(wh0 + 16 * m) * K1 + k] : 0.f;
    };
    auto pf_wh = [&](int c) {
        const int k = c * KC + wk;
        #pragma unroll
        for (int m = 0; m < 10; ++m) pw[m] = Wh[(wh0 + 16 * m) * HD + k];
    };

    pf_a1(0); pf_wi(0);
    for (int c = 0; c < NC1; ++c) {
        const int buf = c & 1;
        At[buf][skq * 4 + 0][se] = pa.x;
        At[buf][skq * 4 + 1][se] = pa.y;
        At[buf][skq * 4 + 2][se] = pa.z;
        At[buf][skq * 4 + 3][se] = pa.w;
        #pragma unroll
        for (int m = 0; m < 10; ++m) Wt[buf][wk][wh0 + 16 * m] = pw[m];
        __syncthreads();
        if (c + 1 < NC1) { pf_a1(c + 1); pf_wi(c + 1); }
        gemm_chunk(acc, At[buf], Wt[buf], tr, tc);
    }
    float h0r[4][10];
    #pragma unroll
    for (int j = 0; j < 10; ++j) {
        const float b = bi[tc * 10 + j];
        #pragma unroll
        for (int i = 0; i < 4; ++i) {
            const float v = acc[i][j] + b;
            h0r[i][j] = v > 0.f ? v : 0.f;
            acc[i][j] = 0.f;
        }
    }

    __syncthreads();
    pa = *(const float4*)(mrow + skq * 4);
    pr = *(const ushort4*)(rrow + skq * 4);
    pf_wh(0);
    for (int c = 0; c < NC2; ++c) {
        const int buf = c & 1;
        At[buf][skq * 4 + 0][se] = pa.x - b2f(pr.x);
        At[buf][skq * 4 + 1][se] = pa.y - b2f(pr.y);
        At[buf][skq * 4 + 2][se] = pa.z - b2f(pr.z);
        At[buf][skq * 4 + 3][se] = pa.w - b2f(pr.w);
        #pragma unroll
        for (int m = 0; m < 10; ++m) Wt[buf][wk][wh0 + 16 * m] = pw[m];
        __syncthreads();
        if (c + 1 < NC2) {
            const int kb = (c + 1) * KC + skq * 4;
            pa = *(const float4*)(mrow + kb);
            pr = *(const ushort4*)(rrow + kb);
            pf_wh(c + 1);
        }
        gemm_chunk(acc, At[buf], Wt[buf], tr, tc);
    }

    #pragma unroll
    for (int i = 0; i < 4; ++i) {
        const long e = base + tr * 4 + i;
        if (e >= E_EDGES) break;
        unsigned short* hp = Hb + e * HD + tc * 10;
        #pragma unroll
        for (int j = 0; j < 10; j += 2) {
            float v0 = h0r[i][j]     + acc[i][j]     + bh[tc * 10 + j];
            float v1 = h0r[i][j + 1] + acc[i][j + 1] + bh[tc * 10 + j + 1];
            v0 = v0 > 0.f ? v0 : 0.f;
            v1 = v1 > 0.f ? v1 : 0.f;
            *(ushort2*)(hp + j) = make_ushort2(f2b(v0), f2b(v1));
        }
    }
}

// ---- k_out (both paths) ----
__global__ __launch_bounds__(256, 2)
void k_out(const float* __restrict__ x, const float* __restrict__ Mg,
           const float* __restrict__ Wo, const float* __restrict__ bo,
           float* __restrict__ out)
{
    __shared__ float At[KC][TE + 4];
    __shared__ float Wt[KC][HD + 8];

    const int  t    = threadIdx.x;
    const long base = (long)blockIdx.x * TE;
    const int  se  = t >> 2;
    const int  skq = t & 3;
    const long gn  = base + se;
    const bool ev  = gn < N_NODES;
    const long gnc = ev ? gn : 0;
    const float* xrow = x  + gnc * HD;
    const float* mrow = Mg + gnc * HD;
    const int tr = t >> 4, tc = t & 15;

    float acc[4][10];
    #pragma unroll
    for (int i = 0; i < 4; ++i)
        #pragma unroll
        for (int j = 0; j < 10; ++j) acc[i][j] = 0.f;

    for (int c = 0; c < KO / KC; ++c) {
        const int k0 = c * KC;
        __syncthreads();
        {
            const int kb = k0 + skq * 4;
            const float4 v = (kb < HD) ? *(const float4*)(xrow + kb)
                                       : *(const float4*)(mrow + (kb - HD));
            At[skq * 4 + 0][se] = v.x;
            At[skq * 4 + 1][se] = v.y;
            At[skq * 4 + 2][se] = v.z;
            At[skq * 4 + 3][se] = v.w;
        }
        for (int i = t; i < HD * KC; i += 256) {
            const int kk = i & (KC - 1);
            const int h  = i >> 4;
            Wt[kk][h] = Wo[h * KO + k0 + kk];
        }
        __syncthreads();
        gemm_chunk(acc, At, Wt, tr, tc);
    }
    #pragma unroll
    for (int i = 0; i < 4; ++i) {
        const long n = base + tr * 4 + i;
        if (n >= N_NODES) break;
        float* op = out + n * HD + tc * 10;
        #pragma unroll
        for (int j = 0; j < 10; j += 2) {
            float v0 = acc[i][j]     + bo[tc * 10 + j];
            float v1 = acc[i][j + 1] + bo[tc * 10 + j + 1];
            v0 = v0 > 0.f ? v0 : 0.f;
            v1 = v1 > 0.f ? v1 : 0.f;
            *(float2*)(op + j) = make_float2(v0, v1);
        }
    }
}

// ---------------------------------------------------------------------------
extern "C" void kernel_launch(void* const* d_in, const int* in_sizes, int n_in,
                              void* d_out, int out_size, void* d_ws, size_t ws_size,
                              hipStream_t stream)
{
    const float* x  = (const float*)d_in[0];
    const float* ea = (const float*)d_in[1];
    const int*   ei = (const int*)d_in[2];
    const float* Wi = (const float*)d_in[4];
    const float* bi = (const float*)d_in[5];
    const float* Wh = (const float*)d_in[6];
    const float* bh = (const float*)d_in[7];
    const float* Wo = (const float*)d_in[8];
    const float* bo = (const float*)d_in[9];
    float* out = (float*)d_out;

    const int* src = ei;
    const int* dst = ei + E_EDGES;

    const int gE  = (E_EDGES + TE - 1) / TE;      // 7813
    const int gE2 = (E_EDGES + TE2 - 1) / TE2;    // 3907
    const int gN  = (N_NODES + TE - 1) / TE;      // 782
    const int gF  = (N_NODES + 3) / 4;            // 12500
    const int gEe = (E_EDGES + 255) / 256;        // 1954

    // FAT:  Hb@0 (160e6) | H0b@160e6 (160e6) | S@320e6 (32e6)
    //       ptr@352e6 | cnt@352,200,016 | cur@352,400,016 | eid@352,600,016
    //       end = 354,600,016
    // MID:  Hb@0 (160e6) | S@160e6 (32e6) | ptr@192e6 | cnt/cur | eid -> 194.6e6
    const size_t NEED_FAT = 355000000;

    if (ws_size >= NEED_FAT) {
        char* w = (char*)d_ws;
        unsigned short* Hb  = (unsigned short*)(w);
        unsigned short* H0b = (unsigned short*)(w + 160000000);
        float* S   = (float*)(w + 320000000);
        int*   ptr = (int*)  (w + 352000000);
        int*   cnt = (int*)  (w + 352200016);
        int*   cur = (int*)  (w + 352400016);
        int*   eid = (int*)  (w + 352600016);
        float* S1  = out;

        k_zero<<<(100000 + 1023) / 1024, 256, 0, stream>>>((float*)cnt, 100000);
        k_csr_count<<<gEe, 256, 0, stream>>>(dst, cnt);
        k_csr_scan<<<1, 1024, 0, stream>>>(cnt, ptr);
        k_csr_fill<<<gEe, 256, 0, stream>>>(dst, ptr, cur, eid);

        k_h0b<<<gE, 256, 0, stream>>>(x, ea, src, Wi, bi, Hb, H0b);
        k_segb<false><<<gF, 256, 0, stream>>>(Hb, ptr, eid, x, S);     // S0
        k_updb2<<<gE2, 256, 0, stream>>>(S, H0b, src, Wh, bh, Hb);     // H1
        k_segb<false><<<gF, 256, 0, stream>>>(Hb, ptr, eid, x, S1);    // S1
        k_updb2<<<gE2, 256, 0, stream>>>(S1, H0b, src, Wh, bh, Hb);    // H2
        k_segb<true ><<<gF, 256, 0, stream>>>(Hb, ptr, eid, x, S);     // M (+fix)
        k_out<<<gN, 256, 0, stream>>>(x, S, Wo, bo, out);
    } else {
        // MID (proven R6 path): ws >= 195MB established by R6 run.
        char* w = (char*)d_ws;
        unsigned short* Hb = (unsigned short*)(w);
        float* S   = (float*)(w + 160000000);
        int*   ptr = (int*)  (w + 192000000);
        int*   cnt = (int*)  (w + 192200016);
        int*   cur = (int*)  (w + 192400016);
        int*   eid = (int*)  (w + 192600016);
        float* S1  = out;

        k_zero<<<(100000 + 1023) / 1024, 256, 0, stream>>>((float*)cnt, 100000);
        k_csr_count<<<gEe, 256, 0, stream>>>(dst, cnt);
        k_csr_scan<<<1, 1024, 0, stream>>>(cnt, ptr);
        k_csr_fill<<<gEe, 256, 0, stream>>>(dst, ptr, cur, eid);

        k_h0b<<<gE, 256, 0, stream>>>(x, ea, src, Wi, bi, Hb, nullptr);
        k_segb<false><<<gF, 256, 0, stream>>>(Hb, ptr, eid, x, S);
        k_updb<<<gE, 256, 0, stream>>>(S, x, ea, src, Wi, bi, Wh, bh, Hb);
        k_segb<false><<<gF, 256, 0, stream>>>(Hb, ptr, eid, x, S1);
        k_updb<<<gE, 256, 0, stream>>>(S1, x, ea, src, Wi, bi, Wh, bh, Hb);
        k_segb<true ><<<gF, 256, 0, stream>>>(Hb, ptr, eid, x, S);
        k_out<<<gN, 256, 0, stream>>>(x, S, Wo, bo, out);
    }
}

// Round 8
// 3550.843 us; speedup vs baseline: 1.2398x; 1.2398x over previous
//
#include <hip/hip_runtime.h>

// Chemprop BondMessagePassing, DEPTH=3, eval mode.
// ws bracket: [195e6, 355e6) proven (R6 ran MID @195e6; R7 FAT @355e6 fell
// back). Bet: ws == E*HD*4 = 320e6 exactly (the fp32 H array size).
// FAT3 (needs EXACTLY 320e6 ws): Hb(bf16,160e6) + H0b(bf16,160e6) in ws.
//   d_out hosts: middle segsums S0/S1 in bf16 (16e6) + CSR (2.6e6).
//   Final segsum (fp32 + x-fallback) goes into the H0b region (dead by then);
//   k_out reads M from ws -> no out aliasing.
//   k_updb2: TE=128, 8x10 tiles, 10 chunks, no H0 recompute -> FMA-bound.
// MID fallback: byte-identical R6 path (proven 3.58ms).

#define E_EDGES 500000
#define N_NODES 50000
#define HD      160
#define BD      14
#define K1      174
#define K1P     176
#define KO      320

#define TE 64
#define KC 16
#define NC1 (K1P / KC)  // 11
#define NC2 (HD / KC)   // 10
#define TE2 128
#define WP  (HD + 8)    // Wt stride, legacy kernels
#define WP2 (HD + 10)   // Wt stride, TE2 kernels (conflict-free staging)

// ---- bf16 helpers (RNE) ----
__device__ __forceinline__ unsigned short f2b(float v) {
    unsigned u = __float_as_uint(v);
    u += 0x7FFFu + ((u >> 16) & 1u);
    return (unsigned short)(u >> 16);
}
__device__ __forceinline__ float b2f(unsigned short h) {
    return __uint_as_float(((unsigned)h) << 16);
}

// ---------------------------------------------------------------------------
__global__ void k_zero(float* __restrict__ p, long n)
{
    const long i = (long)blockIdx.x * 1024 + (long)threadIdx.x * 4;
    if (i + 3 < n) *(float4*)(p + i) = make_float4(0.f, 0.f, 0.f, 0.f);
}

// ---------------------------------------------------------------------------
__device__ __forceinline__
void gemm_chunk(float acc[4][10], const float At[KC][TE + 4],
                const float Wt[KC][WP], int tr, int tc)
{
    #pragma unroll
    for (int k = 0; k < KC; ++k) {
        const float4 a  = *(const float4*)&At[k][tr * 4];
        const float* wp = &Wt[k][tc * 10];
        float w[10];
        #pragma unroll
        for (int j = 0; j < 10; j += 2) {
            const float2 w2 = *(const float2*)(wp + j);
            w[j] = w2.x; w[j + 1] = w2.y;
        }
        #pragma unroll
        for (int j = 0; j < 10; ++j) {
            acc[0][j] = fmaf(a.x, w[j], acc[0][j]);
            acc[1][j] = fmaf(a.y, w[j], acc[1][j]);
            acc[2][j] = fmaf(a.z, w[j], acc[2][j]);
            acc[3][j] = fmaf(a.w, w[j], acc[3][j]);
        }
    }
}

// ============================ CSR build ====================================
__global__ void k_csr_count(const int* __restrict__ dst, int* __restrict__ cnt)
{
    const int e = blockIdx.x * 256 + threadIdx.x;
    if (e < E_EDGES) atomicAdd(&cnt[dst[e]], 1);
}

#define BPT 49
__global__ __launch_bounds__(1024)
void k_csr_scan(const int* __restrict__ cnt, int* __restrict__ ptr)
{
    __shared__ int part[1024];
    const int t  = threadIdx.x;
    const int lo = t * BPT;
    const int hi = min(lo + BPT, N_NODES);
    int s = 0;
    for (int i = lo; i < hi; ++i) s += cnt[i];
    part[t] = s;
    __syncthreads();
    for (int off = 1; off < 1024; off <<= 1) {
        int v = 0;
        if (t >= off) v = part[t - off];
        __syncthreads();
        if (t >= off) part[t] += v;
        __syncthreads();
    }
    int run = (t == 0) ? 0 : part[t - 1];
    for (int i = lo; i < hi; ++i) { ptr[i] = run; run += cnt[i]; }
    if (t == 1023) ptr[N_NODES] = part[1023];
}

__global__ void k_csr_fill(const int* __restrict__ dst, const int* __restrict__ ptr,
                           int* __restrict__ cur, int* __restrict__ eid)
{
    const int e = blockIdx.x * 256 + threadIdx.x;
    if (e < E_EDGES) {
        const int d   = dst[e];
        const int pos = atomicAdd(&cur[d], 1);
        eid[ptr[d] + pos] = e;
    }
}

// ============================ FAT3 kernels (TE2) ===========================

// ---- k_h0b2: Hb[e] = H0b[e] = bf16(relu(Wi @ [x[src]; ea] + bi)) ----
__global__ __launch_bounds__(256, 3)
void k_h0b2(const float* __restrict__ x, const float* __restrict__ ea,
            const int* __restrict__ src,
            const float* __restrict__ Wi, const float* __restrict__ bi,
            unsigned short* __restrict__ Hb, unsigned short* __restrict__ H0b)
{
    __shared__ float At[2][KC][TE2 + 4];
    __shared__ float Wt[2][KC][WP2];

    const int  t    = threadIdx.x;
    const long base = (long)blockIdx.x * TE2;
    const int  sr   = t >> 1;          // staged row
    const int  sq   = t & 1;           // k-half (8 floats)
    const long ge   = base + sr;
    const bool ev   = ge < E_EDGES;
    const long gec  = ev ? ge : 0;
    const int  sidx = ev ? src[gec] : 0;
    const float* xrow = x  + (long)sidx * HD;
    const float* erow = ea + gec * BD;
    const int wk = t & 15, wh0 = t >> 4;
    const int tr = t >> 4, tc = t & 15;

    float4 pa0, pa1; float pw[10];
    float acc[8][10];
    #pragma unroll
    for (int i = 0; i < 8; ++i)
        #pragma unroll
        for (int j = 0; j < 10; ++j) acc[i][j] = 0.f;

    auto pf_a = [&](int c) {
        const int kb = c * KC + sq * 8;
        if (kb + 7 < HD) {
            pa0 = *(const float4*)(xrow + kb);
            pa1 = *(const float4*)(xrow + kb + 4);
        } else {
            float tmp[8];
            #pragma unroll
            for (int j = 0; j < 8; ++j) {
                const int k = kb + j;
                tmp[j] = (k < HD) ? xrow[k] : ((k < K1) ? erow[k - HD] : 0.f);
            }
            pa0 = make_float4(tmp[0], tmp[1], tmp[2], tmp[3]);
            pa1 = make_float4(tmp[4], tmp[5], tmp[6], tmp[7]);
        }
    };
    auto pf_w = [&](int c) {
        const int k = c * KC + wk;
        #pragma unroll
        for (int m = 0; m < 10; ++m)
            pw[m] = (k < K1) ? Wi[(wh0 + 16 * m) * K1 + k] : 0.f;
    };

    pf_a(0); pf_w(0);
    for (int c = 0; c < NC1; ++c) {
        const int buf = c & 1;
        const int kb  = sq * 8;
        At[buf][kb + 0][sr] = pa0.x;
        At[buf][kb + 1][sr] = pa0.y;
        At[buf][kb + 2][sr] = pa0.z;
        At[buf][kb + 3][sr] = pa0.w;
        At[buf][kb + 4][sr] = pa1.x;
        At[buf][kb + 5][sr] = pa1.y;
        At[buf][kb + 6][sr] = pa1.z;
        At[buf][kb + 7][sr] = pa1.w;
        #pragma unroll
        for (int m = 0; m < 10; ++m) Wt[buf][wk][wh0 + 16 * m] = pw[m];
        __syncthreads();
        if (c + 1 < NC1) { pf_a(c + 1); pf_w(c + 1); }
        #pragma unroll
        for (int k = 0; k < KC; ++k) {
            const float4 a0 = *(const float4*)&At[buf][k][tr * 8];
            const float4 a1 = *(const float4*)&At[buf][k][tr * 8 + 4];
            const float* wp = &Wt[buf][k][tc * 10];
            float w[10];
            #pragma unroll
            for (int j = 0; j < 10; j += 2) {
                const float2 w2 = *(const float2*)(wp + j);
                w[j] = w2.x; w[j + 1] = w2.y;
            }
            #pragma unroll
            for (int j = 0; j < 10; ++j) {
                acc[0][j] = fmaf(a0.x, w[j], acc[0][j]);
                acc[1][j] = fmaf(a0.y, w[j], acc[1][j]);
                acc[2][j] = fmaf(a0.z, w[j], acc[2][j]);
                acc[3][j] = fmaf(a0.w, w[j], acc[3][j]);
                acc[4][j] = fmaf(a1.x, w[j], acc[4][j]);
                acc[5][j] = fmaf(a1.y, w[j], acc[5][j]);
                acc[6][j] = fmaf(a1.z, w[j], acc[6][j]);
                acc[7][j] = fmaf(a1.w, w[j], acc[7][j]);
            }
        }
    }
    #pragma unroll
    for (int i = 0; i < 8; ++i) {
        const long e = base + tr * 8 + i;
        if (e >= E_EDGES) break;
        unsigned short* hp  = Hb  + e * HD + tc * 10;
        unsigned short* h0p = H0b + e * HD + tc * 10;
        #pragma unroll
        for (int j = 0; j < 10; j += 2) {
            float v0 = acc[i][j]     + bi[tc * 10 + j];
            float v1 = acc[i][j + 1] + bi[tc * 10 + j + 1];
            v0 = v0 > 0.f ? v0 : 0.f;
            v1 = v1 > 0.f ? v1 : 0.f;
            const ushort2 pv = make_ushort2(f2b(v0), f2b(v1));
            *(ushort2*)(hp + j)  = pv;
            *(ushort2*)(h0p + j) = pv;
        }
    }
}

// ---- k_segb3<MODE>: segment-sum of Hb rows via CSR gather.
// MODE 0: write bf16 Sb. MODE 1: write fp32 S with sum==0 -> x fallback. ----
template <int MODE>
__global__ void k_segb3(const unsigned short* __restrict__ Hb,
                        const int* __restrict__ ptr, const int* __restrict__ eid,
                        const float* __restrict__ x,
                        unsigned short* __restrict__ Sb, float* __restrict__ S)
{
    const int  lane = threadIdx.x & 63;
    const int  w    = threadIdx.x >> 6;
    const long n    = (long)blockIdx.x * 4 + w;
    if (n >= N_NODES) return;
    const int p0 = ptr[n], p1 = ptr[n + 1];
    float a0 = 0.f, a1 = 0.f, a2 = 0.f;
    for (int i = p0; i < p1; ++i) {
        const unsigned short* row = Hb + (long)eid[i] * HD;
        a0 += b2f(row[lane]);
        a1 += b2f(row[64 + lane]);
        if (lane < 32) a2 += b2f(row[128 + lane]);
    }
    const long sb = n * HD;
    if (MODE == 1) {
        float s = a0 + a1 + a2;
        #pragma unroll
        for (int off = 32; off > 0; off >>= 1) s += __shfl_xor(s, off, 64);
        if (s == 0.f) {
            S[sb + lane]      = x[sb + lane];
            S[sb + 64 + lane] = x[sb + 64 + lane];
            if (lane < 32) S[sb + 128 + lane] = x[sb + 128 + lane];
            return;
        }
        S[sb + lane]      = a0;
        S[sb + 64 + lane] = a1;
        if (lane < 32) S[sb + 128 + lane] = a2;
    } else {
        Sb[sb + lane]      = f2b(a0);
        Sb[sb + 64 + lane] = f2b(a1);
        if (lane < 32) Sb[sb + 128 + lane] = f2b(a2);
    }
}

// ---- k_updb2: Hb[e] = bf16(relu(H0b[e] + Wh @ (Sb[src[e]] - Hb[e^1]) + bh))
// TE2=128 rows; 10 chunks; no H0 recompute. In-place Hb safe: rev pairs
// tile-local; all rev prefetches drained (vmcnt0) at the last barrier before
// any epilogue store. ----
__global__ __launch_bounds__(256, 3)
void k_updb2(const unsigned short* __restrict__ Sb,
             const unsigned short* __restrict__ H0b,
             const int* __restrict__ src,
             const float* __restrict__ Wh, const float* __restrict__ bh,
             unsigned short* __restrict__ Hb)
{
    __shared__ float At[2][KC][TE2 + 4];
    __shared__ float Wt[2][KC][WP2];

    const int  t    = threadIdx.x;
    const long base = (long)blockIdx.x * TE2;
    const int  sr   = t >> 1;
    const int  sq   = t & 1;
    const long ge   = base + sr;
    const bool ev   = ge < E_EDGES;
    const long gec  = ev ? ge : 0;
    const int  sidx = ev ? src[gec] : 0;
    const unsigned short* mrow = Sb + (long)sidx * HD;
    const unsigned short* rrow = Hb + (gec ^ 1) * HD;
    const int wk = t & 15, wh0 = t >> 4;
    const int tr = t >> 4, tc = t & 15;

    ushort4 pm0, pm1, pr0, pr1; float pw[10];
    float acc[8][10];
    #pragma unroll
    for (int i = 0; i < 8; ++i)
        #pragma unroll
        for (int j = 0; j < 10; ++j) acc[i][j] = 0.f;

    auto pf_m = [&](int c) {
        const int kb = c * KC + sq * 8;
        pm0 = *(const ushort4*)(mrow + kb);
        pm1 = *(const ushort4*)(mrow + kb + 4);
        pr0 = *(const ushort4*)(rrow + kb);
        pr1 = *(const ushort4*)(rrow + kb + 4);
    };
    auto pf_w = [&](int c) {
        const int k = c * KC + wk;
        #pragma unroll
        for (int m = 0; m < 10; ++m) pw[m] = Wh[(wh0 + 16 * m) * HD + k];
    };

    pf_m(0); pf_w(0);
    for (int c = 0; c < NC2; ++c) {
        const int buf = c & 1;
        const int kb  = sq * 8;
        At[buf][kb + 0][sr] = b2f(pm0.x) - b2f(pr0.x);
        At[buf][kb + 1][sr] = b2f(pm0.y) - b2f(pr0.y);
        At[buf][kb + 2][sr] = b2f(pm0.z) - b2f(pr0.z);
        At[buf][kb + 3][sr] = b2f(pm0.w) - b2f(pr0.w);
        At[buf][kb + 4][sr] = b2f(pm1.x) - b2f(pr1.x);
        At[buf][kb + 5][sr] = b2f(pm1.y) - b2f(pr1.y);
        At[buf][kb + 6][sr] = b2f(pm1.z) - b2f(pr1.z);
        At[buf][kb + 7][sr] = b2f(pm1.w) - b2f(pr1.w);
        #pragma unroll
        for (int m = 0; m < 10; ++m) Wt[buf][wk][wh0 + 16 * m] = pw[m];
        __syncthreads();
        if (c + 1 < NC2) { pf_m(c + 1); pf_w(c + 1); }
        #pragma unroll
        for (int k = 0; k < KC; ++k) {
            const float4 a0 = *(const float4*)&At[buf][k][tr * 8];
            const float4 a1 = *(const float4*)&At[buf][k][tr * 8 + 4];
            const float* wp = &Wt[buf][k][tc * 10];
            float w[10];
            #pragma unroll
            for (int j = 0; j < 10; j += 2) {
                const float2 w2 = *(const float2*)(wp + j);
                w[j] = w2.x; w[j + 1] = w2.y;
            }
            #pragma unroll
            for (int j = 0; j < 10; ++j) {
                acc[0][j] = fmaf(a0.x, w[j], acc[0][j]);
                acc[1][j] = fmaf(a0.y, w[j], acc[1][j]);
                acc[2][j] = fmaf(a0.z, w[j], acc[2][j]);
                acc[3][j] = fmaf(a0.w, w[j], acc[3][j]);
                acc[4][j] = fmaf(a1.x, w[j], acc[4][j]);
                acc[5][j] = fmaf(a1.y, w[j], acc[5][j]);
                acc[6][j] = fmaf(a1.z, w[j], acc[6][j]);
                acc[7][j] = fmaf(a1.w, w[j], acc[7][j]);
            }
        }
    }

    #pragma unroll
    for (int i = 0; i < 8; ++i) {
        const long e = base + tr * 8 + i;
        if (e >= E_EDGES) break;
        const unsigned short* h0p = H0b + e * HD + tc * 10;
        unsigned short*       hp  = Hb  + e * HD + tc * 10;
        #pragma unroll
        for (int j = 0; j < 10; j += 2) {
            const ushort2 h0 = *(const ushort2*)(h0p + j);
            float v0 = b2f(h0.x) + acc[i][j]     + bh[tc * 10 + j];
            float v1 = b2f(h0.y) + acc[i][j + 1] + bh[tc * 10 + j + 1];
            v0 = v0 > 0.f ? v0 : 0.f;
            v1 = v1 > 0.f ? v1 : 0.f;
            *(ushort2*)(hp + j) = make_ushort2(f2b(v0), f2b(v1));
        }
    }
}

// ============================ MID kernels (R6, proven) =====================

__global__ __launch_bounds__(256, 3)
void k_h0b(const float* __restrict__ x, const float* __restrict__ ea,
           const int* __restrict__ src,
           const float* __restrict__ Wi, const float* __restrict__ bi,
           unsigned short* __restrict__ Hb)
{
    __shared__ float At[2][KC][TE + 4];
    __shared__ float Wt[2][KC][WP];

    const int  t    = threadIdx.x;
    const long base = (long)blockIdx.x * TE;
    const int  se   = t >> 2;
    const int  skq  = t & 3;
    const long ge   = base + se;
    const bool ev   = ge < E_EDGES;
    const long gec  = ev ? ge : 0;
    const int  sidx = ev ? src[ge] : 0;
    const float* xrow = x  + (long)sidx * HD;
    const float* erow = ea + gec * BD;
    const int wk = t & 15, wh0 = t >> 4;
    const int tr = t >> 4, tc = t & 15;

    float4 pa; float pw[10];
    float acc[4][10];
    #pragma unroll
    for (int i = 0; i < 4; ++i)
        #pragma unroll
        for (int j = 0; j < 10; ++j) acc[i][j] = 0.f;

    auto pf_a = [&](int c) {
        const int kb = c * KC + skq * 4;
        if (kb + 3 < HD) pa = *(const float4*)(xrow + kb);
        else {
            float tmp[4];
            #pragma unroll
            for (int j = 0; j < 4; ++j) {
                const int k = kb + j;
                tmp[j] = (k < HD) ? xrow[k] : ((k < K1) ? erow[k - HD] : 0.f);
            }
            pa = make_float4(tmp[0], tmp[1], tmp[2], tmp[3]);
        }
    };
    auto pf_w = [&](int c) {
        const int k = c * KC + wk;
        #pragma unroll
        for (int m = 0; m < 10; ++m)
            pw[m] = (k < K1) ? Wi[(wh0 + 16 * m) * K1 + k] : 0.f;
    };

    pf_a(0); pf_w(0);
    for (int c = 0; c < NC1; ++c) {
        const int buf = c & 1;
        At[buf][skq * 4 + 0][se] = pa.x;
        At[buf][skq * 4 + 1][se] = pa.y;
        At[buf][skq * 4 + 2][se] = pa.z;
        At[buf][skq * 4 + 3][se] = pa.w;
        #pragma unroll
        for (int m = 0; m < 10; ++m) Wt[buf][wk][wh0 + 16 * m] = pw[m];
        __syncthreads();
        if (c + 1 < NC1) { pf_a(c + 1); pf_w(c + 1); }
        gemm_chunk(acc, At[buf], Wt[buf], tr, tc);
    }
    #pragma unroll
    for (int i = 0; i < 4; ++i) {
        const long e = base + tr * 4 + i;
        if (e >= E_EDGES) break;
        unsigned short* hp = Hb + e * HD + tc * 10;
        #pragma unroll
        for (int j = 0; j < 10; j += 2) {
            float v0 = acc[i][j]     + bi[tc * 10 + j];
            float v1 = acc[i][j + 1] + bi[tc * 10 + j + 1];
            v0 = v0 > 0.f ? v0 : 0.f;
            v1 = v1 > 0.f ? v1 : 0.f;
            *(ushort2*)(hp + j) = make_ushort2(f2b(v0), f2b(v1));
        }
    }
}

template <bool FINAL>
__global__ void k_segb(const unsigned short* __restrict__ Hb,
                       const int* __restrict__ ptr, const int* __restrict__ eid,
                       const float* __restrict__ x, float* __restrict__ S)
{
    const int  lane = threadIdx.x & 63;
    const int  w    = threadIdx.x >> 6;
    const long n    = (long)blockIdx.x * 4 + w;
    if (n >= N_NODES) return;
    const int p0 = ptr[n], p1 = ptr[n + 1];
    float a0 = 0.f, a1 = 0.f, a2 = 0.f;
    for (int i = p0; i < p1; ++i) {
        const unsigned short* row = Hb + (long)eid[i] * HD;
        a0 += b2f(row[lane]);
        a1 += b2f(row[64 + lane]);
        if (lane < 32) a2 += b2f(row[128 + lane]);
    }
    const long sb = n * HD;
    if (FINAL) {
        float s = a0 + a1 + a2;
        #pragma unroll
        for (int off = 32; off > 0; off >>= 1) s += __shfl_xor(s, off, 64);
        if (s == 0.f) {
            S[sb + lane]      = x[sb + lane];
            S[sb + 64 + lane] = x[sb + 64 + lane];
            if (lane < 32) S[sb + 128 + lane] = x[sb + 128 + lane];
            return;
        }
    }
    S[sb + lane]      = a0;
    S[sb + 64 + lane] = a1;
    if (lane < 32) S[sb + 128 + lane] = a2;
}

__global__ __launch_bounds__(256, 3)
void k_updb(const float* __restrict__ S,
            const float* __restrict__ x, const float* __restrict__ ea,
            const int* __restrict__ src,
            const float* __restrict__ Wi, const float* __restrict__ bi,
            const float* __restrict__ Wh, const float* __restrict__ bh,
            unsigned short* __restrict__ Hb)
{
    __shared__ float At[2][KC][TE + 4];
    __shared__ float Wt[2][KC][WP];

    const int  t    = threadIdx.x;
    const long base = (long)blockIdx.x * TE;
    const int  se   = t >> 2;
    const int  skq  = t & 3;
    const long ge   = base + se;
    const bool ev   = ge < E_EDGES;
    const long gec  = ev ? ge : 0;
    const int  sidx = ev ? src[ge] : 0;
    const float* xrow = x  + (long)sidx * HD;
    const float* erow = ea + gec * BD;
    const float* mrow = S  + (long)sidx * HD;
    const unsigned short* rrow = Hb + (gec ^ 1) * HD;
    const int wk = t & 15, wh0 = t >> 4;
    const int tr = t >> 4, tc = t & 15;

    float4 pa; ushort4 pr; float pw[10];
    float acc[4][10];
    #pragma unroll
    for (int i = 0; i < 4; ++i)
        #pragma unroll
        for (int j = 0; j < 10; ++j) acc[i][j] = 0.f;

    auto pf_a1 = [&](int c) {
        const int kb = c * KC + skq * 4;
        if (kb + 3 < HD) pa = *(const float4*)(xrow + kb);
        else {
            float tmp[4];
            #pragma unroll
            for (int j = 0; j < 4; ++j) {
                const int k = kb + j;
                tmp[j] = (k < HD) ? xrow[k] : ((k < K1) ? erow[k - HD] : 0.f);
            }
            pa = make_float4(tmp[0], tmp[1], tmp[2], tmp[3]);
        }
    };
    auto pf_wi = [&](int c) {
        const int k = c * KC + wk;
        #pragma unroll
        for (int m = 0; m < 10; ++m)
            pw[m] = (k < K1) ? Wi[(wh0 + 16 * m) * K1 + k] : 0.f;
    };
    auto pf_wh = [&](int c) {
        const int k = c * KC + wk;
        #pragma unroll
        for (int m = 0; m < 10; ++m) pw[m] = Wh[(wh0 + 16 * m) * HD + k];
    };

    pf_a1(0); pf_wi(0);
    for (int c = 0; c < NC1; ++c) {
        const int buf = c & 1;
        At[buf][skq * 4 + 0][se] = pa.x;
        At[buf][skq * 4 + 1][se] = pa.y;
        At[buf][skq * 4 + 2][se] = pa.z;
        At[buf][skq * 4 + 3][se] = pa.w;
        #pragma unroll
        for (int m = 0; m < 10; ++m) Wt[buf][wk][wh0 + 16 * m] = pw[m];
        __syncthreads();
        if (c + 1 < NC1) { pf_a1(c + 1); pf_wi(c + 1); }
        gemm_chunk(acc, At[buf], Wt[buf], tr, tc);
    }
    float h0r[4][10];
    #pragma unroll
    for (int j = 0; j < 10; ++j) {
        const float b = bi[tc * 10 + j];
        #pragma unroll
        for (int i = 0; i < 4; ++i) {
            const float v = acc[i][j] + b;
            h0r[i][j] = v > 0.f ? v : 0.f;
            acc[i][j] = 0.f;
        }
    }

    __syncthreads();
    pa = *(const float4*)(mrow + skq * 4);
    pr = *(const ushort4*)(rrow + skq * 4);
    pf_wh(0);
    for (int c = 0; c < NC2; ++c) {
        const int buf = c & 1;
        At[buf][skq * 4 + 0][se] = pa.x - b2f(pr.x);
        At[buf][skq * 4 + 1][se] = pa.y - b2f(pr.y);
        At[buf][skq * 4 + 2][se] = pa.z - b2f(pr.z);
        At[buf][skq * 4 + 3][se] = pa.w - b2f(pr.w);
        #pragma unroll
        for (int m = 0; m < 10; ++m) Wt[buf][wk][wh0 + 16 * m] = pw[m];
        __syncthreads();
        if (c + 1 < NC2) {
            const int kb = (c + 1) * KC + skq * 4;
            pa = *(const float4*)(mrow + kb);
            pr = *(const ushort4*)(rrow + kb);
            pf_wh(c + 1);
        }
        gemm_chunk(acc, At[buf], Wt[buf], tr, tc);
    }

    #pragma unroll
    for (int i = 0; i < 4; ++i) {
        const long e = base + tr * 4 + i;
        if (e >= E_EDGES) break;
        unsigned short* hp = Hb + e * HD + tc * 10;
        #pragma unroll
        for (int j = 0; j < 10; j += 2) {
            float v0 = h0r[i][j]     + acc[i][j]     + bh[tc * 10 + j];
            float v1 = h0r[i][j + 1] + acc[i][j + 1] + bh[tc * 10 + j + 1];
            v0 = v0 > 0.f ? v0 : 0.f;
            v1 = v1 > 0.f ? v1 : 0.f;
            *(ushort2*)(hp + j) = make_ushort2(f2b(v0), f2b(v1));
        }
    }
}

// ---- k_out (both paths; Mg fp32, never aliases out) ----
__global__ __launch_bounds__(256, 2)
void k_out(const float* __restrict__ x, const float* __restrict__ Mg,
           const float* __restrict__ Wo, const float* __restrict__ bo,
           float* __restrict__ out)
{
    __shared__ float At[KC][TE + 4];
    __shared__ float Wt[KC][WP];

    const int  t    = threadIdx.x;
    const long base = (long)blockIdx.x * TE;
    const int  se  = t >> 2;
    const int  skq = t & 3;
    const long gn  = base + se;
    const bool ev  = gn < N_NODES;
    const long gnc = ev ? gn : 0;
    const float* xrow = x  + gnc * HD;
    const float* mrow = Mg + gnc * HD;
    const int tr = t >> 4, tc = t & 15;

    float acc[4][10];
    #pragma unroll
    for (int i = 0; i < 4; ++i)
        #pragma unroll
        for (int j = 0; j < 10; ++j) acc[i][j] = 0.f;

    for (int c = 0; c < KO / KC; ++c) {
        const int k0 = c * KC;
        __syncthreads();
        {
            const int kb = k0 + skq * 4;
            const float4 v = (kb < HD) ? *(const float4*)(xrow + kb)
                                       : *(const float4*)(mrow + (kb - HD));
            At[skq * 4 + 0][se] = v.x;
            At[skq * 4 + 1][se] = v.y;
            At[skq * 4 + 2][se] = v.z;
            At[skq * 4 + 3][se] = v.w;
        }
        for (int i = t; i < HD * KC; i += 256) {
            const int kk = i & (KC - 1);
            const int h  = i >> 4;
            Wt[kk][h] = Wo[h * KO + k0 + kk];
        }
        __syncthreads();
        gemm_chunk(acc, At, Wt, tr, tc);
    }
    #pragma unroll
    for (int i = 0; i < 4; ++i) {
        const long n = base + tr * 4 + i;
        if (n >= N_NODES) break;
        float* op = out + n * HD + tc * 10;
        #pragma unroll
        for (int j = 0; j < 10; j += 2) {
            float v0 = acc[i][j]     + bo[tc * 10 + j];
            float v1 = acc[i][j + 1] + bo[tc * 10 + j + 1];
            v0 = v0 > 0.f ? v0 : 0.f;
            v1 = v1 > 0.f ? v1 : 0.f;
            *(float2*)(op + j) = make_float2(v0, v1);
        }
    }
}

// ---------------------------------------------------------------------------
extern "C" void kernel_launch(void* const* d_in, const int* in_sizes, int n_in,
                              void* d_out, int out_size, void* d_ws, size_t ws_size,
                              hipStream_t stream)
{
    const float* x  = (const float*)d_in[0];
    const float* ea = (const float*)d_in[1];
    const int*   ei = (const int*)d_in[2];
    const float* Wi = (const float*)d_in[4];
    const float* bi = (const float*)d_in[5];
    const float* Wh = (const float*)d_in[6];
    const float* bh = (const float*)d_in[7];
    const float* Wo = (const float*)d_in[8];
    const float* bo = (const float*)d_in[9];
    float* out = (float*)d_out;

    const int* src = ei;
    const int* dst = ei + E_EDGES;

    const int gE  = (E_EDGES + TE - 1) / TE;      // 7813
    const int gE2 = (E_EDGES + TE2 - 1) / TE2;    // 3907
    const int gN  = (N_NODES + TE - 1) / TE;      // 782
    const int gF  = (N_NODES + 3) / 4;            // 12500
    const int gEe = (E_EDGES + 255) / 256;        // 1954

    if (ws_size >= 320000000) {
        // FAT3: ws = Hb | H0b (exactly 320e6). out hosts Sb16 + CSR until the
        // final phase; final fp32 M overwrites H0b (dead after upd2).
        char* w = (char*)d_ws;
        char* o = (char*)d_out;
        unsigned short* Hb  = (unsigned short*)(w);
        unsigned short* H0b = (unsigned short*)(w + 160000000);
        unsigned short* Sb  = (unsigned short*)(o);                // 16e6 B
        int*   ptr = (int*)(o + 16000000);                         // 200,016
        int*   cnt = (int*)(o + 16200016);                         // 200,000
        int*   cur = (int*)(o + 16400016);                         // 200,000
        int*   eid = (int*)(o + 16600016);                         // 2e6
        float* Mf  = (float*)H0b;   // final fp32 M reuses H0b region

        k_zero<<<(100000 + 1023) / 1024, 256, 0, stream>>>((float*)cnt, 100000);
        k_csr_count<<<gEe, 256, 0, stream>>>(dst, cnt);
        k_csr_scan<<<1, 1024, 0, stream>>>(cnt, ptr);
        k_csr_fill<<<gEe, 256, 0, stream>>>(dst, ptr, cur, eid);

        k_h0b2<<<gE2, 256, 0, stream>>>(x, ea, src, Wi, bi, Hb, H0b);
        k_segb3<0><<<gF, 256, 0, stream>>>(Hb, ptr, eid, x, Sb, nullptr); // S0
        k_updb2<<<gE2, 256, 0, stream>>>(Sb, H0b, src, Wh, bh, Hb);       // H1
        k_segb3<0><<<gF, 256, 0, stream>>>(Hb, ptr, eid, x, Sb, nullptr); // S1
        k_updb2<<<gE2, 256, 0, stream>>>(Sb, H0b, src, Wh, bh, Hb);       // H2
        k_segb3<1><<<gF, 256, 0, stream>>>(Hb, ptr, eid, x, nullptr, Mf); // M
        k_out<<<gN, 256, 0, stream>>>(x, Mf, Wo, bo, out);
    } else {
        // MID (proven R6 path, ws >= 195e6).
        char* w = (char*)d_ws;
        unsigned short* Hb = (unsigned short*)(w);
        float* S   = (float*)(w + 160000000);
        int*   ptr = (int*)  (w + 192000000);
        int*   cnt = (int*)  (w + 192200016);
        int*   cur = (int*)  (w + 192400016);
        int*   eid = (int*)  (w + 192600016);
        float* S1  = out;

        k_zero<<<(100000 + 1023) / 1024, 256, 0, stream>>>((float*)cnt, 100000);
        k_csr_count<<<gEe, 256, 0, stream>>>(dst, cnt);
        k_csr_scan<<<1, 1024, 0, stream>>>(cnt, ptr);
        k_csr_fill<<<gEe, 256, 0, stream>>>(dst, ptr, cur, eid);

        k_h0b<<<gE, 256, 0, stream>>>(x, ea, src, Wi, bi, Hb);
        k_segb<false><<<gF, 256, 0, stream>>>(Hb, ptr, eid, x, S);
        k_updb<<<gE, 256, 0, stream>>>(S, x, ea, src, Wi, bi, Wh, bh, Hb);
        k_segb<false><<<gF, 256, 0, stream>>>(Hb, ptr, eid, x, S1);
        k_updb<<<gE, 256, 0, stream>>>(S1, x, ea, src, Wi, bi, Wh, bh, Hb);
        k_segb<true ><<<gF, 256, 0, stream>>>(Hb, ptr, eid, x, S);
        k_out<<<gN, 256, 0, stream>>>(x, S, Wo, bo, out);
    }
}